// Round 1
// 420.199 us; speedup vs baseline: 1.0120x; 1.0120x over previous
//
#include <hip/hip_runtime.h>

// WindowMultiHeadAttention: b=4, n=4096, d=1024, H=16, dk=64, WIN=64, nw=64.
// Inputs fp32. Convert once to bf16; GEMMs now use the 256x256xBK64 8-phase
// schedule (T2 granule-swizzle + T3/T4 counted-vmcnt K-half pipeline + T5
// setprio), grid 256 = 1 block/CU, XCD-chunked for B-panel L2 reuse.
// Windowed attention (1 wave/window) unchanged from the 425us baseline.
//
// Buffer plan (unchanged):
//   d_out lower half : Xq (bf16)        -> clobbered by final fp32 C (Xq dead)
//   d_out upper half : qb (bf16 q)      -> dead after proj_q
//   q input buffer   : Wq/Wk/Wv/Wo bf16 (8.4 MB), written AFTER q fully read
//   ws S1 (33.5 MB)  : kb -> vb -> Xo   (serial reuse)
//   ws +33.5MB       : Xk;  ws +67MB : Xv

typedef unsigned short u16;
typedef unsigned int u32;
typedef __bf16 bf16x8 __attribute__((ext_vector_type(8)));
typedef float f32x4 __attribute__((ext_vector_type(4)));
typedef u16 u16x8 __attribute__((ext_vector_type(8)));

__device__ __forceinline__ u16 f2bf(float f) {
  u32 u = __builtin_bit_cast(u32, f);
  u += 0x7fffu + ((u >> 16) & 1u);  // RNE
  return (u16)(u >> 16);
}

__device__ __forceinline__ void cvt8_store(const float* __restrict__ src,
                                           u16* __restrict__ dst, size_t i) {
  const float4 a = *(const float4*)(src + i);
  const float4 b = *(const float4*)(src + i + 4);
  u16x8 r;
  r[0] = f2bf(a.x); r[1] = f2bf(a.y); r[2] = f2bf(a.z); r[3] = f2bf(a.w);
  r[4] = f2bf(b.x); r[5] = f2bf(b.y); r[6] = f2bf(b.z); r[7] = f2bf(b.w);
  *(u16x8*)(dst + i) = r;
}

__global__ __launch_bounds__(256) void cvt_kernel(const float* __restrict__ src,
                                                  u16* __restrict__ dst) {
  cvt8_store(src, dst, ((size_t)blockIdx.x * 256 + threadIdx.x) * 8);
}

__global__ __launch_bounds__(256) void cvtw_kernel(
    const float* __restrict__ Wq, const float* __restrict__ Wk,
    const float* __restrict__ Wv, const float* __restrict__ Wo,
    u16* __restrict__ dst) {
  const float* src = (blockIdx.z == 0) ? Wq : (blockIdx.z == 1) ? Wk
                   : (blockIdx.z == 2) ? Wv : Wo;
  cvt8_store(src, dst + (size_t)blockIdx.z * 1048576,
             ((size_t)blockIdx.x * 256 + threadIdx.x) * 8);
}

__device__ __forceinline__ void cp16(const u16* g, u16* l) {
  // async global->LDS, 16B/lane; LDS dst = wave-uniform base + lane*16.
  __builtin_amdgcn_global_load_lds((const __attribute__((address_space(1))) void*)g,
                                   (__attribute__((address_space(3))) void*)l, 16, 0, 0);
}

// ---------------------------------------------------------------------------
// C[M,N] = A[M,K]*B[N,K]^T, bf16 in, fp32 acc. M=16384, N=K=1024.
// 256x256 tile, BK=64, 512 threads = 8 waves (2M x 4N), LDS 128KB (2 dbuf).
// Staging unit = K-half (256 rows x 32 cols = 16KB = 2 x gload_lds_dwordx4
// per thread). Phase order per K-tile: (mh0,ks0)(mh1,ks0)(mh0,ks1)(mh1,ks1)
// so a unit staged at phase p of tile t is consumed 2-4 phases later in tile
// t+1 -> main loop waits only vmcnt(4), never 0 (single drain in peeled tail).
// LDS granule swizzle: 16B slot phys = row*4 + (g ^ ((row>>1)&3)); applied on
// the GLOBAL source (gload_lds writes linearly) and on the ds_read address.
// Read conflicts: 16 lanes/quad spread 2-per-bank-group = free (m136).
// ---------------------------------------------------------------------------
#define BAR __builtin_amdgcn_s_barrier()
#define LGKM0                                            \
  do {                                                   \
    asm volatile("s_waitcnt lgkmcnt(0)" ::: "memory");   \
    __builtin_amdgcn_sched_barrier(0);                   \
  } while (0)
#define VMC(N) asm volatile("s_waitcnt vmcnt(" #N ")" ::: "memory")

#define MFMA16(MB, KS)                                                       \
  _Pragma("unroll") for (int m_ = 0; m_ < 4; ++m_)                           \
  _Pragma("unroll") for (int n_ = 0; n_ < 4; ++n_)                           \
      acc[(MB) + m_][n_] = __builtin_amdgcn_mfma_f32_16x16x32_bf16(          \
          af[m_], bfr[KS][n_], acc[(MB) + m_][n_], 0, 0, 0)

// One K-tile = 4 phases. CUR/NXT are compile-time 0/1; ST=0 only for the tail.
#define KTILE(CUR, NXT, KO, ST)                                               \
  {                                                                           \
    /* P1: mh0 x ks0 ; prefetch A(kt+1) kh0 */                                \
    _Pragma("unroll") for (int m_ = 0; m_ < 4; ++m_)                          \
        af[m_] = *(const bf16x8*)&LA[CUR][0][abase + m_ * 512];               \
    _Pragma("unroll") for (int n_ = 0; n_ < 4; ++n_)                          \
        bfr[0][n_] = *(const bf16x8*)&LB[CUR][0][bbase + n_ * 512];           \
    if (ST) {                                                                 \
      cp16(As0 + (KO), &LA[NXT][0][ld0]);                                     \
      cp16(As0 + 131072 + (KO), &LA[NXT][0][ld0 + 4096]);                     \
    }                                                                         \
    BAR; LGKM0;                                                               \
    __builtin_amdgcn_s_setprio(1); MFMA16(0, 0); __builtin_amdgcn_s_setprio(0);\
    BAR;                                                                      \
    /* P2: mh1 x ks0 ; prefetch B(kt+1) kh0 */                                \
    _Pragma("unroll") for (int m_ = 0; m_ < 4; ++m_)                          \
        af[m_] = *(const bf16x8*)&LA[CUR][0][abase + 2048 + m_ * 512];        \
    if (ST) {                                                                 \
      cp16(Bs0 + (KO), &LB[NXT][0][ld0]);                                     \
      cp16(Bs0 + 131072 + (KO), &LB[NXT][0][ld0 + 4096]);                     \
    }                                                                         \
    BAR; LGKM0;                                                               \
    __builtin_amdgcn_s_setprio(1); MFMA16(4, 0); __builtin_amdgcn_s_setprio(0);\
    if (ST) { VMC(4); } else { VMC(0); }                                      \
    BAR;                                                                      \
    /* P3: mh0 x ks1 ; prefetch A(kt+1) kh1 */                                \
    _Pragma("unroll") for (int m_ = 0; m_ < 4; ++m_)                          \
        af[m_] = *(const bf16x8*)&LA[CUR][1][abase + m_ * 512];               \
    _Pragma("unroll") for (int n_ = 0; n_ < 4; ++n_)                          \
        bfr[1][n_] = *(const bf16x8*)&LB[CUR][1][bbase + n_ * 512];           \
    if (ST) {                                                                 \
      cp16(As0 + 32 + (KO), &LA[NXT][1][ld0]);                                \
      cp16(As0 + 131104 + (KO), &LA[NXT][1][ld0 + 4096]);                     \
    }                                                                         \
    BAR; LGKM0;                                                               \
    __builtin_amdgcn_s_setprio(1); MFMA16(0, 1); __builtin_amdgcn_s_setprio(0);\
    BAR;                                                                      \
    /* P4: mh1 x ks1 ; prefetch B(kt+1) kh1 */                                \
    _Pragma("unroll") for (int m_ = 0; m_ < 4; ++m_)                          \
        af[m_] = *(const bf16x8*)&LA[CUR][1][abase + 2048 + m_ * 512];        \
    if (ST) {                                                                 \
      cp16(Bs0 + 32 + (KO), &LB[NXT][1][ld0]);                                \
      cp16(Bs0 + 131104 + (KO), &LB[NXT][1][ld0 + 4096]);                     \
    }                                                                         \
    BAR; LGKM0;                                                               \
    __builtin_amdgcn_s_setprio(1); MFMA16(4, 1); __builtin_amdgcn_s_setprio(0);\
    if (ST) { VMC(4); } else { VMC(0); }                                      \
    BAR;                                                                      \
  }

__global__ __launch_bounds__(512, 2) void gemm8_kernel(
    const u16* __restrict__ A, const u16* __restrict__ B, void* __restrict__ Cv,
    int cf) {
  __shared__ u16 LA[2][2][8192];  // [buf][khalf][256 rows x 32 cols], 64KB
  __shared__ u16 LB[2][2][8192];  // 64KB
  const int tid = threadIdx.x;
  const int lane = tid & 63, w = tid >> 6;
  const int wm = w >> 2, wn = w & 3;           // 2M x 4N waves
  const int quad = lane >> 4, lr = lane & 15;
  // XCD-chunked swizzle: 256 wgs, 8 XCDs -> 32 consecutive tiles per XCD,
  // m-fastest so each XCD reuses one 512KB B-panel from L2.
  const int swz = (blockIdx.x & 7) * 32 + (blockIdx.x >> 3);
  const int m0 = (swz & 63) * 256, n0 = (swz >> 6) * 256;

  // Staging: thread covers 16B slots s0=tid and s1=tid+512 of each unit.
  // slot s -> row = s>>2, phys granule = s&3, logical granule = (s&3)^((row>>1)&3).
  // s1 = s0 + 512 -> row+128, same granule swizzle -> src offset +128 rows.
  const int r0 = tid >> 2;
  const int gsw = ((tid & 3) ^ ((r0 >> 1) & 3)) * 8;  // u16 units
  const u16* As0 = A + (size_t)(m0 + r0) * 1024 + gsw;
  const u16* Bs0 = B + (size_t)(n0 + r0) * 1024 + gsw;
  const int ld0 = tid * 8;  // u16 index of instr-0 LDS slot (instr1 = +4096)

  // Fragment reads: row stride 32 u16 (64B); granule = quad ^ ((lr>>1)&3).
  const int qsw = (quad ^ ((lr >> 1) & 3)) << 3;
  const int abase = (wm * 128 + lr) * 32 + qsw;  // + mh*2048 + m*512
  const int bbase = (wn * 64 + lr) * 32 + qsw;   // + ni*512

  f32x4 acc[8][4] = {};
  bf16x8 af[4], bfr[2][4];

  // Prologue: K-tile 0 -> buf0, order (Akh0,Bkh0,Akh1,Bkh1); vmcnt(4) leaves
  // the kh1 units in flight (consumed only at P3, re-checked at P2-end).
  cp16(As0, &LA[0][0][ld0]);      cp16(As0 + 131072, &LA[0][0][ld0 + 4096]);
  cp16(Bs0, &LB[0][0][ld0]);      cp16(Bs0 + 131072, &LB[0][0][ld0 + 4096]);
  cp16(As0 + 32, &LA[0][1][ld0]); cp16(As0 + 131104, &LA[0][1][ld0 + 4096]);
  cp16(Bs0 + 32, &LB[0][1][ld0]); cp16(Bs0 + 131104, &LB[0][1][ld0 + 4096]);
  VMC(4);
  BAR;

#pragma unroll 1
  for (int kt = 0; kt < 14; kt += 2) {
    const int ko1 = (kt + 1) * 64, ko2 = (kt + 2) * 64;
    KTILE(0, 1, ko1, 1);
    KTILE(1, 0, ko2, 1);
  }
  KTILE(0, 1, 15 * 64, 1);  // kt = 14, prefetches kt 15
  KTILE(1, 0, 0, 0);        // kt = 15, tail: no prefetch, vmcnt(0) drain

  // Epilogue. C/D frag layout: row = quad*4+r, col = lr (m89-verified).
#pragma unroll
  for (int mi = 0; mi < 8; ++mi)
#pragma unroll
    for (int r = 0; r < 4; ++r) {
      const int row = m0 + wm * 128 + mi * 16 + quad * 4 + r;
      if (!cf) {
        u16* dst = (u16*)Cv + (size_t)row * 1024 + n0 + wn * 64 + lr;
#pragma unroll
        for (int ni = 0; ni < 4; ++ni) dst[ni * 16] = f2bf(acc[mi][ni][r]);
      } else {
        float* dst = (float*)Cv + (size_t)row * 1024 + n0 + wn * 64 + lr;
#pragma unroll
        for (int ni = 0; ni < 4; ++ni) dst[ni * 16] = acc[mi][ni][r];
      }
    }
}

// One wave per (b, h, window). 64q x 64k x dk=64, bf16. LDS = P only (9.2 KB).
__global__ __launch_bounds__(64) void attn_win_kernel(
    const u16* __restrict__ Xq, const u16* __restrict__ Xk, const u16* __restrict__ Xv,
    u16* __restrict__ Xo) {
  __shared__ u16 P[64 * 72];  // [qp][kp], stride 72 keeps 16B row alignment
  const int bx = blockIdx.x;  // 0..4095
  const int wi = bx & 63, h = (bx >> 6) & 15, b = bx >> 10;
  const int lane = threadIdx.x & 63, quad = lane >> 4, lr = lane & 15;
  const size_t tb = (size_t)b * 4096 + wi * 64;  // window = 64 contiguous tokens
  const u16* qb = Xq + tb * 1024 + h * 64;
  const u16* kb = Xk + tb * 1024 + h * 64;
  const u16* vb = Xv + tb * 1024 + h * 64;

  // S = Q K^T: A-frag Q[m=lr+16mi][k=quad*8+j+32ks]; B-frag K[n=lr+16ni][k]
  bf16x8 aq[4][2], bk[4][2];
#pragma unroll
  for (int mi = 0; mi < 4; ++mi)
#pragma unroll
    for (int ks = 0; ks < 2; ++ks) {
      aq[mi][ks] = *(const bf16x8*)(qb + (size_t)(mi * 16 + lr) * 1024 + ks * 32 + quad * 8);
      bk[mi][ks] = *(const bf16x8*)(kb + (size_t)(mi * 16 + lr) * 1024 + ks * 32 + quad * 8);
    }
  f32x4 s[4][4];
#pragma unroll
  for (int mi = 0; mi < 4; ++mi)
#pragma unroll
    for (int ni = 0; ni < 4; ++ni) {
      f32x4 z = {0.f, 0.f, 0.f, 0.f};
      z = __builtin_amdgcn_mfma_f32_16x16x32_bf16(aq[mi][0], bk[ni][0], z, 0, 0, 0);
      s[mi][ni] = __builtin_amdgcn_mfma_f32_16x16x32_bf16(aq[mi][1], bk[ni][1], z, 0, 0, 0);
    }

  // V B-frags from global, overlapping the softmax latency:
  u16x8 bvr[2][4];
#pragma unroll
  for (int ks = 0; ks < 2; ++ks)
#pragma unroll
    for (int ci = 0; ci < 4; ++ci) {
      const u16* vc = vb + (size_t)(ks * 32 + quad * 8) * 1024 + ci * 16 + lr;
#pragma unroll
      for (int j = 0; j < 8; ++j) bvr[ks][ci][j] = vc[(size_t)j * 1024];
    }

  // softmax: row (quad*4+r of tile mi) spans this quad's 16 lanes x 4 ni regs
  const float sc = 0.125f;  // 1/sqrt(64)
#pragma unroll
  for (int mi = 0; mi < 4; ++mi)
#pragma unroll
    for (int r = 0; r < 4; ++r) {
      float mx = fmaxf(fmaxf(s[mi][0][r], s[mi][1][r]), fmaxf(s[mi][2][r], s[mi][3][r]));
#pragma unroll
      for (int m = 1; m < 16; m <<= 1) mx = fmaxf(mx, __shfl_xor(mx, m));
      float sum = 0.f;
#pragma unroll
      for (int ni = 0; ni < 4; ++ni) {
        float p = __expf((s[mi][ni][r] - mx) * sc);
        s[mi][ni][r] = p;
        sum += p;
      }
#pragma unroll
      for (int m = 1; m < 16; m <<= 1) sum += __shfl_xor(sum, m);
      const float inv = 1.f / sum;
#pragma unroll
      for (int ni = 0; ni < 4; ++ni) s[mi][ni][r] *= inv;
    }

  // P (C/D layout) -> LDS row-major
#pragma unroll
  for (int mi = 0; mi < 4; ++mi)
#pragma unroll
    for (int ni = 0; ni < 4; ++ni)
#pragma unroll
      for (int r = 0; r < 4; ++r)
        P[(mi * 16 + quad * 4 + r) * 72 + ni * 16 + lr] = f2bf(s[mi][ni][r]);
  __syncthreads();  // single wave: compiles to lgkmcnt drain

  // O = P V
  f32x4 o[4][4] = {};
#pragma unroll
  for (int ks = 0; ks < 2; ++ks) {
    bf16x8 ap[4];
#pragma unroll
    for (int mi = 0; mi < 4; ++mi)
      ap[mi] = *(const bf16x8*)&P[(mi * 16 + lr) * 72 + ks * 32 + quad * 8];
#pragma unroll
    for (int mi = 0; mi < 4; ++mi)
#pragma unroll
      for (int ci = 0; ci < 4; ++ci)
        o[mi][ci] = __builtin_amdgcn_mfma_f32_16x16x32_bf16(
            ap[mi], __builtin_bit_cast(bf16x8, bvr[ks][ci]), o[mi][ci], 0, 0, 0);
  }

  // reference permutation: out token = qp*64 + wi
#pragma unroll
  for (int mi = 0; mi < 4; ++mi)
#pragma unroll
    for (int r = 0; r < 4; ++r) {
      const int qp = mi * 16 + quad * 4 + r;
      u16* dst = Xo + ((size_t)b * 4096 + (size_t)qp * 64 + wi) * 1024 + h * 64 + lr;
#pragma unroll
      for (int ci = 0; ci < 4; ++ci) dst[ci * 16] = f2bf(o[mi][ci][r]);
    }
}

extern "C" void kernel_launch(void* const* d_in, const int* in_sizes, int n_in,
                              void* d_out, int out_size, void* d_ws, size_t ws_size,
                              hipStream_t stream) {
  (void)in_sizes; (void)n_in; (void)out_size; (void)ws_size;
  const float* q  = (const float*)d_in[0];
  const float* k  = (const float*)d_in[1];
  const float* v  = (const float*)d_in[2];
  const float* Wq = (const float*)d_in[3];
  const float* Wk = (const float*)d_in[4];
  const float* Wv = (const float*)d_in[5];
  const float* Wo = (const float*)d_in[6];

  constexpr size_t ELEMS = (size_t)16384 * 1024;
  u16* Xq = (u16*)d_out;          // d_out lower half
  u16* qb = (u16*)d_out + ELEMS;  // d_out upper half
  u16* Wb = (u16*)d_in[0];        // bf16 weights in q's buffer (after q consumed)
  u16* S1 = (u16*)d_ws;           // serial scratch: kb -> vb -> Xo
  u16* Xk = S1 + ELEMS;
  u16* Xv = Xk + ELEMS;
  u16* Xo = S1;

  cvt_kernel<<<8192, 256, 0, stream>>>(q, qb);
  cvtw_kernel<<<dim3(512, 1, 4), 256, 0, stream>>>(Wq, Wk, Wv, Wo, Wb);
  cvt_kernel<<<8192, 256, 0, stream>>>(k, S1);
  gemm8_kernel<<<256, 512, 0, stream>>>(qb, Wb, Xq, 0);
  gemm8_kernel<<<256, 512, 0, stream>>>(S1, Wb + 1048576, Xk, 0);
  cvt_kernel<<<8192, 256, 0, stream>>>(v, S1);
  gemm8_kernel<<<256, 512, 0, stream>>>(S1, Wb + 2097152, Xv, 0);
  attn_win_kernel<<<dim3(4096), 64, 0, stream>>>(Xq, Xk, Xv, Xo);
  gemm8_kernel<<<256, 512, 0, stream>>>(Xo, Wb + 3145728, (float*)d_out, 1);
}